// Round 11
// baseline (392.282 us; speedup 1.0000x reference)
//
#include <hip/hip_runtime.h>
#include <cstdint>

#define EMBD 1024
#define NH 16
#define DH 64
#define BB 2
#define SS 2048
#define M_TOT (BB*SS)     // 4096
#define N_QKV (3*EMBD)    // 3072
#define GRID 512
#define NTHREADS (GRID*256)

typedef __bf16 bf16_t;
typedef bf16_t bf16x8 __attribute__((ext_vector_type(8)));
typedef float f32x4 __attribute__((ext_vector_type(4)));
typedef unsigned short u16;
typedef unsigned int u32;

static __device__ __forceinline__ u16 f2bf(float f) {
    union { float f; unsigned u; } c; c.f = f;
    unsigned u = c.u;
    unsigned r = (u + 0x7FFFu + ((u >> 16) & 1u)) >> 16;  // RNE
    return (u16)r;
}

// async global->LDS, 16B per lane; LDS dest must be wave-uniform base + lane*16
#define GLDS16(gp, lp) \
    __builtin_amdgcn_global_load_lds((const __attribute__((address_space(1))) void*)(gp), \
                                     (__attribute__((address_space(3))) void*)(lp), 16, 0, 0)

// ---- persistent grid barrier: monotonic counter, release/acquire, agent scope
__device__ unsigned g_bar = 0;
static __device__ __forceinline__ void grid_sync() {
    __syncthreads();
    if (threadIdx.x == 0) {
        __threadfence();   // agent-scope release (flush L1, L2 writeback)
        unsigned old = __hip_atomic_fetch_add(&g_bar, 1u, __ATOMIC_ACQ_REL,
                                              __HIP_MEMORY_SCOPE_AGENT);
        unsigned target = (old / GRID + 1u) * GRID;
        while (__hip_atomic_load(&g_bar, __ATOMIC_ACQUIRE,
                                 __HIP_MEMORY_SCOPE_AGENT) < target)
            __builtin_amdgcn_s_sleep(8);
        __threadfence();   // agent-scope acquire (invalidate stale lines)
    }
    __syncthreads();
}

#define NX8 (M_TOT * EMBD / 8)          // 524288
#define NWI8 (N_QKV * EMBD / 8)         // 393216
#define NWO8 (EMBD * EMBD / 8)          // 131072
#define QSCALE (0.125f * 1.4426950408889634f)
#define OST 72

static __device__ __forceinline__ void cast8(const float* __restrict__ s,
                                             u16* __restrict__ d, int off) {
    const float4* s4 = (const float4*)s;
    float4 a = s4[2 * off];
    float4 b = s4[2 * off + 1];
    union { u16 u[8]; uint4 v; } r;
    r.u[0] = f2bf(a.x); r.u[1] = f2bf(a.y); r.u[2] = f2bf(a.z); r.u[3] = f2bf(a.w);
    r.u[4] = f2bf(b.x); r.u[5] = f2bf(b.y); r.u[6] = f2bf(b.z); r.u[7] = f2bf(b.w);
    ((uint4*)d)[off] = r.v;
}

__global__ __launch_bounds__(256, 2) void fused_attn(
    const float* __restrict__ x, const float* __restrict__ W_in,
    const float* __restrict__ b_in, const float* __restrict__ W_out,
    const float* __restrict__ b_out,
    u16* __restrict__ xb, u16* __restrict__ wib, u16* __restrict__ wob,
    u16* __restrict__ Q, u16* __restrict__ Kf, u16* __restrict__ Vpf,
    u16* __restrict__ AO, float* __restrict__ Out)
{
    __shared__ u16 SH[32768];    // 64 KB, reused by every phase
    const int t = threadIdx.x;
    const int bx = blockIdx.x;
    const int lane = t & 63, w = t >> 6;
    const int quad = lane >> 4, l16 = lane & 15;
    const int wm = w >> 1, wn = w & 1;

    // ================= phase 0: cast fp32 -> bf16 =================
    {
        int tid = bx * 256 + t;
        for (int g = tid; g < NX8; g += NTHREADS)  cast8(x, xb, g);
        for (int g = tid; g < NWI8; g += NTHREADS) cast8(W_in, wib, g);
        for (int g = tid; g < NWO8; g += NTHREADS) cast8(W_out, wob, g);
    }
    grid_sync();

    // ================= phase 1: QKV GEMM (128x192 tile, dbuf DMA) ==========
    // Q [B,H,S,64] (x QSCALE); Kf fragment-linear; Vpf frag-linear k-permuted.
    {
        const int m0 = (bx >> 4) * 128;
        const int n0 = (bx & 15) * 192;
        const int sA0 = t, sA1 = 256 + t;
        const int sB0 = t, sB1 = 256 + t, sB2 = 512 + t;
        const u16* gA0 = xb + (size_t)(m0 + (sA0 >> 2)) * EMBD + (sA0 & 3) * 8;
        const u16* gA1 = xb + (size_t)(m0 + (sA1 >> 2)) * EMBD + (sA1 & 3) * 8;
        const u16* gB0 = wib + (size_t)(n0 + (sB0 >> 2)) * EMBD + (sB0 & 3) * 8;
        const u16* gB1 = wib + (size_t)(n0 + (sB1 >> 2)) * EMBD + (sB1 & 3) * 8;
        const u16* gB2 = wib + (size_t)(n0 + (sB2 >> 2)) * EMBD + (sB2 & 3) * 8;

        f32x4 acc[4][6] = {};

        {   // prologue: tile 0 -> buf 0  (buf stride 10240 u16: A 4096 | B 6144)
            u16* buf = SH;
            GLDS16(gA0, buf + sA0 * 8); GLDS16(gA1, buf + sA1 * 8);
            GLDS16(gB0, buf + 4096 + sB0 * 8); GLDS16(gB1, buf + 4096 + sB1 * 8);
            GLDS16(gB2, buf + 4096 + sB2 * 8);
        }
        for (int it = 0; it < EMBD / 32; ++it) {
            asm volatile("s_waitcnt vmcnt(0)" ::: "memory");
            __syncthreads();
            if (it + 1 < EMBD / 32) {
                int k0 = (it + 1) * 32;
                u16* buf = SH + ((it + 1) & 1) * 10240;
                GLDS16(gA0 + k0, buf + sA0 * 8); GLDS16(gA1 + k0, buf + sA1 * 8);
                GLDS16(gB0 + k0, buf + 4096 + sB0 * 8);
                GLDS16(gB1 + k0, buf + 4096 + sB1 * 8);
                GLDS16(gB2 + k0, buf + 4096 + sB2 * 8);
            }
            const u16* As = SH + (it & 1) * 10240;
            const u16* Bs = As + 4096;
            bf16x8 af[4], bfr[6];
#pragma unroll
            for (int im = 0; im < 4; ++im)
                af[im] = *(const bf16x8*)(As + (wm * 64 + im * 16 + l16) * 32 + quad * 8);
#pragma unroll
            for (int in = 0; in < 6; ++in)
                bfr[in] = *(const bf16x8*)(Bs + (wn * 96 + in * 16 + l16) * 32 + quad * 8);
#pragma unroll
            for (int im = 0; im < 4; ++im)
#pragma unroll
                for (int in = 0; in < 6; ++in)
                    acc[im][in] = __builtin_amdgcn_mfma_f32_16x16x32_bf16(
                        af[im], bfr[in], acc[im][in], 0, 0, 0);
        }
        // epilogue: C/D layout col=lane&15, row=quad*4+reg
#pragma unroll
        for (int im = 0; im < 4; ++im) {
            int rbase = m0 + wm * 64 + im * 16 + quad * 4;
            int b = rbase >> 11, ss = rbase & (SS - 1);
#pragma unroll
            for (int in = 0; in < 6; ++in) {
                int col = n0 + wn * 96 + in * 16 + l16;
                float bias = b_in[col];
                float v0 = acc[im][in][0] + bias;
                float v1 = acc[im][in][1] + bias;
                float v2 = acc[im][in][2] + bias;
                float v3 = acc[im][in][3] + bias;
                if (col < EMBD) {
                    int h = col >> 6, d = col & 63;
                    u16* qp = Q + (((size_t)(b * NH + h) * SS) + ss) * DH + d;
                    qp[0]      = f2bf(v0 * QSCALE);
                    qp[DH]     = f2bf(v1 * QSCALE);
                    qp[2 * DH] = f2bf(v2 * QSCALE);
                    qp[3 * DH] = f2bf(v3 * QSCALE);
                } else if (col < 2 * EMBD) {
                    int c = col - EMBD; int h = c >> 6, d = c & 63;
                    u16* kp = Kf + (size_t)(b * NH + h) * SS * DH
                              + (ss >> 4) * 1024 + (d >> 5) * 512
                              + (ss & 15) * 32 + ((d >> 3) & 3) * 8 + (d & 7);
                    kp[0]  = f2bf(v0);
                    kp[32] = f2bf(v1);
                    kp[64] = f2bf(v2);
                    kp[96] = f2bf(v3);
                } else {
                    int c = col - 2 * EMBD; int h = c >> 6, d = c & 63;
                    int p32 = ((ss >> 2) & 3) * 8 + ((ss >> 4) & 1) * 4;
                    u32 lo = (u32)f2bf(v0) | ((u32)f2bf(v1) << 16);
                    u32 hi = (u32)f2bf(v2) | ((u32)f2bf(v3) << 16);
                    uint2 pk; pk.x = lo; pk.y = hi;
                    *(uint2*)(Vpf + (size_t)(b * NH + h) * SS * DH
                              + (ss >> 5) * 2048 + (d >> 4) * 512 + (d & 15) * 32 + p32) = pk;
                }
            }
        }
    }
    grid_sync();

    // ================= phase 2: attention (128-key tiles, dbuf DMA) ========
    {
        const int bh = (bx & 7) * 4 + ((bx >> 3) & 3);   // XCD-clustered heads
        const int qt = bx >> 5;
        const int q0 = qt * 128 + w * 32;

        const u16* Qh = Q + ((size_t)bh * SS + q0) * DH;
        const u16* Kh = Kf + (size_t)bh * SS * DH;
        const u16* Vh = Vpf + (size_t)bh * SS * DH;

        bf16x8 qb[2][2];
#pragma unroll
        for (int qi = 0; qi < 2; ++qi) {
            qb[qi][0] = *(const bf16x8*)(Qh + (qi * 16 + l16) * DH + quad * 8);
            qb[qi][1] = *(const bf16x8*)(Qh + (qi * 16 + l16) * DH + 32 + quad * 8);
        }

        f32x4 o[2][4] = {};
        float lsum[2] = {0.f, 0.f};

#pragma unroll
        for (int i = 0; i < 4; ++i) {   // chunk 0 -> buf 0 (buf: K 8192 | V 8192)
            GLDS16(Kh + i * 2048 + t * 8, SH + i * 2048 + t * 8);
            GLDS16(Vh + i * 2048 + t * 8, SH + 8192 + i * 2048 + t * 8);
        }

        for (int it = 0; it < SS / 128; ++it) {
            asm volatile("s_waitcnt vmcnt(0)" ::: "memory");
            __syncthreads();
            if (it + 1 < SS / 128) {
                const u16* kc = Kh + (it + 1) * 8192;
                const u16* vc = Vh + (it + 1) * 8192;
                u16* kb = SH + ((it + 1) & 1) * 16384;
                u16* vb = kb + 8192;
#pragma unroll
                for (int i = 0; i < 4; ++i) {
                    GLDS16(kc + i * 2048 + t * 8, kb + i * 2048 + t * 8);
                    GLDS16(vc + i * 2048 + t * 8, vb + i * 2048 + t * 8);
                }
            }
            const u16* Kb = SH + (it & 1) * 16384;
            const u16* Vb = Kb + 8192;
#pragma unroll
            for (int g = 0; g < 4; ++g) {
                bf16x8 ka00 = *(const bf16x8*)(Kb + (2 * g) * 1024 +       l16 * 32 + quad * 8);
                bf16x8 ka01 = *(const bf16x8*)(Kb + (2 * g) * 1024 + 512 + l16 * 32 + quad * 8);
                bf16x8 ka10 = *(const bf16x8*)(Kb + (2 * g + 1) * 1024 +       l16 * 32 + quad * 8);
                bf16x8 ka11 = *(const bf16x8*)(Kb + (2 * g + 1) * 1024 + 512 + l16 * 32 + quad * 8);
                bf16x8 va0 = *(const bf16x8*)(Vb + g * 2048 +        l16 * 32 + quad * 8);
                bf16x8 va1 = *(const bf16x8*)(Vb + g * 2048 + 512  + l16 * 32 + quad * 8);
                bf16x8 va2 = *(const bf16x8*)(Vb + g * 2048 + 1024 + l16 * 32 + quad * 8);
                bf16x8 va3 = *(const bf16x8*)(Vb + g * 2048 + 1536 + l16 * 32 + quad * 8);
                bf16x8 pb[2];
#pragma unroll
                for (int qi = 0; qi < 2; ++qi) {
                    f32x4 z0 = {0.f, 0.f, 0.f, 0.f};
                    f32x4 z1 = {0.f, 0.f, 0.f, 0.f};
                    z0 = __builtin_amdgcn_mfma_f32_16x16x32_bf16(ka00, qb[qi][0], z0, 0, 0, 0);
                    z0 = __builtin_amdgcn_mfma_f32_16x16x32_bf16(ka01, qb[qi][1], z0, 0, 0, 0);
                    z1 = __builtin_amdgcn_mfma_f32_16x16x32_bf16(ka10, qb[qi][0], z1, 0, 0, 0);
                    z1 = __builtin_amdgcn_mfma_f32_16x16x32_bf16(ka11, qb[qi][1], z1, 0, 0, 0);
                    u32 ue[8];
                    float ls = 0.f;
#pragma unroll
                    for (int j = 0; j < 4; ++j) {
                        float e0 = __builtin_amdgcn_exp2f(z0[j]);
                        float e1 = __builtin_amdgcn_exp2f(z1[j]);
                        ls += e0 + e1;
                        union { float f; u32 v; } c0, c1;
                        c0.f = e0; c1.f = e1;
                        ue[j] = c0.v + 0x8000u;      // round-half-up to bf16
                        ue[4 + j] = c1.v + 0x8000u;
                    }
                    lsum[qi] += ls;
                    union { uint4 u; bf16x8 b; } cv;
                    cv.u.x = __builtin_amdgcn_perm(ue[1], ue[0], 0x07060302u);
                    cv.u.y = __builtin_amdgcn_perm(ue[3], ue[2], 0x07060302u);
                    cv.u.z = __builtin_amdgcn_perm(ue[5], ue[4], 0x07060302u);
                    cv.u.w = __builtin_amdgcn_perm(ue[7], ue[6], 0x07060302u);
                    pb[qi] = cv.b;
                }
                o[0][0] = __builtin_amdgcn_mfma_f32_16x16x32_bf16(va0, pb[0], o[0][0], 0, 0, 0);
                o[0][1] = __builtin_amdgcn_mfma_f32_16x16x32_bf16(va1, pb[0], o[0][1], 0, 0, 0);
                o[0][2] = __builtin_amdgcn_mfma_f32_16x16x32_bf16(va2, pb[0], o[0][2], 0, 0, 0);
                o[0][3] = __builtin_amdgcn_mfma_f32_16x16x32_bf16(va3, pb[0], o[0][3], 0, 0, 0);
                o[1][0] = __builtin_amdgcn_mfma_f32_16x16x32_bf16(va0, pb[1], o[1][0], 0, 0, 0);
                o[1][1] = __builtin_amdgcn_mfma_f32_16x16x32_bf16(va1, pb[1], o[1][1], 0, 0, 0);
                o[1][2] = __builtin_amdgcn_mfma_f32_16x16x32_bf16(va2, pb[1], o[1][2], 0, 0, 0);
                o[1][3] = __builtin_amdgcn_mfma_f32_16x16x32_bf16(va3, pb[1], o[1][3], 0, 0, 0);
            }
        }

        float rl[2];
#pragma unroll
        for (int qi = 0; qi < 2; ++qi) {
            float v = lsum[qi];
            v += __shfl_xor(v, 16, 64);
            v += __shfl_xor(v, 32, 64);
            rl[qi] = 1.0f / v;
        }
        __syncthreads();
#pragma unroll
        for (int qi = 0; qi < 2; ++qi)
#pragma unroll
            for (int dt = 0; dt < 4; ++dt)
#pragma unroll
                for (int jj = 0; jj < 2; ++jj) {
                    u32 lo_ = (u32)f2bf(o[qi][dt][2 * jj] * rl[qi]);
                    u32 hi_ = (u32)f2bf(o[qi][dt][2 * jj + 1] * rl[qi]);
                    *(u32*)(SH + (w * 32 + qi * 16 + l16) * OST + dt * 16 + quad * 4 + jj * 2) =
                        lo_ | (hi_ << 16);
                }
        __syncthreads();
        const int b = bh >> 4, h = bh & 15;
#pragma unroll
        for (int i = 0; i < 4; ++i) {
            int idx = i * 256 + t;
            int q = idx >> 3, c = idx & 7;
            uint4 vv = *(const uint4*)(SH + q * OST + c * 8);
            *(uint4*)(AO + ((size_t)(b * SS + qt * 128 + q)) * EMBD + h * DH + c * 8) = vv;
        }
    }
    grid_sync();

    // ================= phase 3: out projection (128x64 tile, dbuf DMA) =====
    {
        const int m0 = (bx >> 4) * 128;
        const int n0 = (bx & 15) * 64;
        const int sA0 = t, sA1 = 256 + t;
        const int sB0 = t;                       // 64 rows x 4 chunks = 256 slots
        const u16* gA0 = AO + (size_t)(m0 + (sA0 >> 2)) * EMBD + (sA0 & 3) * 8;
        const u16* gA1 = AO + (size_t)(m0 + (sA1 >> 2)) * EMBD + (sA1 & 3) * 8;
        const u16* gB0 = wob + (size_t)(n0 + (sB0 >> 2)) * EMBD + (sB0 & 3) * 8;

        f32x4 acc[4][2] = {};

        {   // buf stride 8192 u16: A 4096 | B 2048
            u16* buf = SH;
            GLDS16(gA0, buf + sA0 * 8); GLDS16(gA1, buf + sA1 * 8);
            GLDS16(gB0, buf + 4096 + sB0 * 8);
        }
        for (int it = 0; it < EMBD / 32; ++it) {
            asm volatile("s_waitcnt vmcnt(0)" ::: "memory");
            __syncthreads();
            if (it + 1 < EMBD / 32) {
                int k0 = (it + 1) * 32;
                u16* buf = SH + ((it + 1) & 1) * 8192;
                GLDS16(gA0 + k0, buf + sA0 * 8); GLDS16(gA1 + k0, buf + sA1 * 8);
                GLDS16(gB0 + k0, buf + 4096 + sB0 * 8);
            }
            const u16* As = SH + (it & 1) * 8192;
            const u16* Bs = As + 4096;
            bf16x8 af[4], bfr[2];
#pragma unroll
            for (int im = 0; im < 4; ++im)
                af[im] = *(const bf16x8*)(As + (wm * 64 + im * 16 + l16) * 32 + quad * 8);
#pragma unroll
            for (int in = 0; in < 2; ++in)
                bfr[in] = *(const bf16x8*)(Bs + (wn * 32 + in * 16 + l16) * 32 + quad * 8);
#pragma unroll
            for (int im = 0; im < 4; ++im)
#pragma unroll
                for (int in = 0; in < 2; ++in)
                    acc[im][in] = __builtin_amdgcn_mfma_f32_16x16x32_bf16(
                        af[im], bfr[in], acc[im][in], 0, 0, 0);
        }
#pragma unroll
        for (int im = 0; im < 4; ++im) {
            int rbase = m0 + wm * 64 + im * 16 + quad * 4;
#pragma unroll
            for (int in = 0; in < 2; ++in) {
                int col = n0 + wn * 32 + in * 16 + l16;
                float bias = b_out[col];
#pragma unroll
                for (int j = 0; j < 4; ++j)
                    Out[(size_t)(rbase + j) * EMBD + col] = acc[im][in][j] + bias;
            }
        }
    }
}

extern "C" void kernel_launch(void* const* d_in, const int* in_sizes, int n_in,
                              void* d_out, int out_size, void* d_ws, size_t ws_size,
                              hipStream_t stream)
{
    (void)in_sizes; (void)n_in; (void)out_size; (void)ws_size;
    const float* x     = (const float*)d_in[0];
    const float* W_in  = (const float*)d_in[1];
    const float* b_in  = (const float*)d_in[2];
    const float* W_out = (const float*)d_in[3];
    const float* b_out = (const float*)d_in[4];
    float* out = (float*)d_out;

    char* ws = (char*)d_ws;
    u16* xb  = (u16*)(ws);                          //  8 MB
    u16* wib = (u16*)(ws + 8u  * 1024 * 1024);      //  6 MB
    u16* wob = (u16*)(ws + 14u * 1024 * 1024);      //  2 MB
    u16* Qw  = (u16*)(ws + 16u * 1024 * 1024);      //  8 MB
    u16* Kw  = (u16*)(ws + 24u * 1024 * 1024);      //  8 MB
    u16* Vpw = (u16*)(ws + 32u * 1024 * 1024);      //  8 MB
    u16* AO  = (u16*)(ws + 40u * 1024 * 1024);      //  8 MB

    fused_attn<<<GRID, 256, 0, stream>>>(x, W_in, b_in, W_out, b_out,
                                         xb, wib, wob, Qw, Kw, Vpw, AO, out);
}